// Round 2
// baseline (374.776 us; speedup 1.0000x reference)
//
#include <hip/hip_runtime.h>

#define BB 64
#define LL 512
#define TT 52
#define START_TAG 50
#define END_TAG 51
#define CH 32               // chunk size (rows) for feats staging + bp window
#define CF (CH * TT)        // floats per chunk = 1664
#define NCHUNK (LL / CH)    // 16

__device__ __forceinline__ unsigned umin32(unsigned a, unsigned b) { return a < b ? a : b; }

// Partial argmax over this wave's 13 sources vs the global max M.
// Key byte = matching global index, or 64 (inline-const sentinel) on miss.
// Min over the wave's 13 keys here, then min over the 4 wave-bytes at
// compaction == smallest global index with value==M == jnp.argmax
// first-max-wins (value-compare, so even the +-0 corner matches reference).
// Template WB keeps bv[] indices compile-time constant (no scratch spill).
template<int WB>
__device__ __forceinline__ unsigned argmax13(const float (&bv)[TT], float M) {
    unsigned kk[13];
    #pragma unroll
    for (int q = 0; q < 13; ++q)
        kk[q] = (bv[WB + q] == M) ? (unsigned)(WB + q) : 64u;
    unsigned k0 = umin32(umin32(kk[0], kk[1]), kk[2]);
    unsigned k1 = umin32(umin32(kk[3], kk[4]), kk[5]);
    unsigned k2 = umin32(umin32(kk[6], kk[7]), kk[8]);
    unsigned k3 = umin32(umin32(kk[9], kk[10]), kk[11]);
    return umin32(umin32(umin32(k0, k1), umin32(k2, k3)), kk[12]);
}

// R10: barrier-free replicated recurrence (R9) + LDS feats staging (R8).
// R9's regression was the per-step global f load: rolled loop => compiler
// emits s_waitcnt vmcnt(0) every step (~900 cy exposed). Now f comes from a
// 32-row double-buffered LDS chunk (ds_read issued one step early, ~120 cy
// covered by ~480 cy of VALU). Staging is split T14-style: global loads for
// chunk h+3 issued at epilogue h (one full chunk of cover), ds_write at
// epilogue h+1, so no vmcnt wait is ever exposed. All cross-wave LDS
// hand-offs (bp window, feats buffers) are ordered by the 2 barriers per
// 32-step chunk (32 barriers total vs R8's 511).
// Exactness: (f + c[i]) + P[i] order identical to reference; max tree exact
// in any order; all 4 waves compute bit-identical bestP (same inputs, same
// op order); argmax = first-max-wins as in jnp.argmax.
__launch_bounds__(256, 1)
__global__ void viterbi_kernel(const float* __restrict__ feats,
                               const int* __restrict__ mask,
                               const float* __restrict__ trans,
                               int* __restrict__ out) {
    const int b    = blockIdx.x;
    const int tid  = threadIdx.x;
    const int lane = tid & 63;
    const int w    = tid >> 6;

    __shared__ float s_feat[2][CF];                // feats chunks, double-buffered (13312 B)
    __shared__ unsigned int  s_bpw32[CH * TT];     // bp-key window: 4 B per (row,tag) (6656 B)
    __shared__ unsigned char s_bp[LL * TT];        // final backpointers (26624 B)
    __shared__ int s_tags[LL];
    __shared__ unsigned char s_map[8 * 52];
    __shared__ int s_ent[8];

    // ---- length n = sum(mask[b,:]) ----
    int partial = 0;
    const int* mrow = mask + b * LL;
    #pragma unroll
    for (int k = 0; k < LL / 64; ++k) partial += mrow[lane + 64 * k];
    #pragma unroll
    for (int off = 32; off >= 1; off >>= 1) partial += __shfl_xor(partial, off, 64);
    const int n = partial;  // uniform, in [256, 512]

    const int flane = (lane < TT) ? lane : (TT - 1);   // clamped: in-bounds everywhere
    const float* frow = feats + (size_t)b * LL * TT;

    // ---- full transition column per lane (replicated in every wave) ----
    float creg[TT];
    #pragma unroll
    for (int i = 0; i < TT; ++i) creg[i] = trans[i * TT + flane];
    const float tE = trans[flane * TT + END_TAG];

    // ---- P0 in-register ----
    float bestP = (lane < TT) ? (frow[lane] + trans[START_TAG * TT + lane]) : -3.0e38f;

    #pragma unroll
    for (int k = 0; k < LL / 256; ++k) s_tags[tid + 256 * k] = 0;

    // ---- preload chunks 0 and 1 ----
    #pragma unroll
    for (int k = 0; k < 7; ++k) {
        int idx = k * 256 + tid;
        if (idx < CF) {
            s_feat[0][idx] = frow[idx];
            s_feat[1][idx] = frow[CF + idx];
        }
    }
    __syncthreads();

    float fcur = s_feat[0][TT + flane];   // f for t=1

    unsigned char* bpw = (unsigned char*)s_bpw32;
    const int myByte = (lane < TT) ? (lane * 4 + w) : 0;   // byte slot in window row

    // ---- pending staging loads (issue-early / write-late) ----
    float pend[7];
    #pragma unroll
    for (int k = 0; k < 7; ++k) {                // issue loads for chunk 2
        int idx = k * 256 + tid;
        pend[k] = (idx < CF) ? frow[2 * CF + idx] : 0.0f;
    }

    // ---- one step: f from register, next f via LDS (issued early) ----
    auto step = [&](int t, float f, float& fnext_out) {
        int tn = t + 1; if (tn > LL - 1) tn = LL - 1;
        float fnx = s_feat[(tn >> 5) & 1][(tn & (CH - 1)) * TT + flane];

        // bv[i] = (f[t][j] + trans[i][j]) + P[i]   -- exact reference order
        float bv[TT];
        #pragma unroll
        for (int i = 0; i < TT; ++i) {
            float Pi = __int_as_float(__builtin_amdgcn_readlane(__float_as_int(bestP), i));
            bv[i] = (f + creg[i]) + Pi;
        }

        // 52-value max tree (max3-shaped; max exact in any order)
        float l1[18];
        #pragma unroll
        for (int g = 0; g < 17; ++g)
            l1[g] = fmaxf(fmaxf(bv[3 * g], bv[3 * g + 1]), bv[3 * g + 2]);
        l1[17] = bv[51];
        float l2[6];
        #pragma unroll
        for (int g = 0; g < 6; ++g)
            l2[g] = fmaxf(fmaxf(l1[3 * g], l1[3 * g + 1]), l1[3 * g + 2]);
        float M = fmaxf(fmaxf(fmaxf(l2[0], l2[1]), fmaxf(l2[2], l2[3])),
                        fmaxf(l2[4], l2[5]));

        unsigned km;
        if      (w == 0) km = argmax13<0 >(bv, M);
        else if (w == 1) km = argmax13<13>(bv, M);
        else if (w == 2) km = argmax13<26>(bv, M);
        else             km = argmax13<39>(bv, M);

        bestP = M;   // bit-identical across all 4 waves

        if (lane < TT)
            bpw[(t & (CH - 1)) * (TT * 4) + myByte] = (unsigned char)km;  // byte-disjoint

        fnext_out = fnx;
    };

    // ---- forward: 32-step chunks; barriers only at chunk boundaries ----
    int t = 1;
    for (int h = 0; CH * h < n; ++h) {
        int tend = CH * (h + 1); if (tend > n) tend = n;
        for (; t < tend; ++t) step(t, fcur, fcur);

        __syncthreads();   // bp window complete; chunk-h feats buffer dead

        // compact window h -> s_bp (min of 4 wave-keys, &63)
        #pragma unroll
        for (int k = 0; k < 7; ++k) {
            int e = k * 256 + tid;                   // e = row*52 + j
            if (e < CF) {
                unsigned wv = s_bpw32[e];
                unsigned mm = umin32(umin32(wv & 255u, (wv >> 8) & 255u),
                                     umin32((wv >> 16) & 255u, wv >> 24)) & 63u;
                s_bp[h * CF + e] = (unsigned char)mm;
            }
        }

        // write pending chunk h+2 into the just-freed buffer (vmcnt long since 0)
        if (h + 2 < NCHUNK) {
            float* dp = s_feat[h & 1];               // (h+2)&1 == h&1
            #pragma unroll
            for (int k = 0; k < 7; ++k) {
                int idx = k * 256 + tid;
                if (idx < CF) dp[idx] = pend[k];
            }
        }

        __syncthreads();   // staging + compaction visible before next chunk

        // issue loads for chunk h+3 (consumed at next epilogue; full chunk of cover)
        if (h + 3 < NCHUNK) {
            const float* sp = frow + (h + 3) * CF;
            #pragma unroll
            for (int k = 0; k < 7; ++k) {
                int idx = k * 256 + tid;
                if (idx < CF) pend[k] = sp[idx];
            }
        }
    }

    // ---- pointer0 = argmax_i ( P_{n-1}[i] + trans[i,END] ), min-index tie ----
    float lv = (lane < TT) ? (bestP + tE) : -3.0e38f;
    int li = lane;
    #pragma unroll
    for (int off = 32; off >= 1; off >>= 1) {
        float ov = __shfl_xor(lv, off, 64);
        int   oi = __shfl_xor(li, off, 64);
        if (ov > lv || (ov == lv && oi < li)) { lv = ov; li = oi; }
    }
    const int ptr0 = li;

    __syncthreads();

    // ---- backtrace: 8-chunk two-phase parallel pointer chase ----
    const int W  = n - 1;
    const int Sc = (W + 7) >> 3;
    {
        int v0 = tid;
        int k0 = v0 / 52, y0 = v0 - k0 * 52;
        int v1 = tid + 256;
        bool a1 = (v1 < 416);
        int k1 = a1 ? v1 / 52 : 7, y1 = a1 ? (v1 - k1 * 52) : 0;
        int s0a = k0 * Sc, s1a = min(s0a + Sc, W);
        int s0b = k1 * Sc, s1b = min(s0b + Sc, W);
        int xa = y0, xb = y1;
        for (int s = 0; s < Sc; ++s) {
            int ga = s0a + s, gb = s0b + s;
            if (ga < s1a) xa = s_bp[(n - 1 - ga) * TT + xa];
            if (gb < s1b) xb = s_bp[(n - 1 - gb) * TT + xb];
        }
        s_map[k0 * 52 + y0] = (unsigned char)xa;
        if (a1) s_map[k1 * 52 + y1] = (unsigned char)xb;
    }
    __syncthreads();
    if (tid == 0) {
        int e = ptr0; s_ent[0] = e;
        #pragma unroll
        for (int k = 1; k < 8; ++k) { e = s_map[(k - 1) * 52 + e]; s_ent[k] = e; }
        s_tags[n - 1] = ptr0;
        s_tags[LL - 1] = ptr0;   // reference quirk: decode[L-1] = pointer0 always
    }
    __syncthreads();
    if (tid < 8) {
        int k = tid;
        int x = s_ent[k];
        int ss0 = k * Sc, ss1 = min(ss0 + Sc, W);
        for (int s = ss0; s < ss1; ++s) {
            x = s_bp[(n - 1 - s) * TT + x];
            s_tags[n - 2 - s] = x;
        }
    }
    __syncthreads();

    // ---- coalesced output write ----
    int* orow = out + b * LL;
    #pragma unroll
    for (int k = 0; k < LL / 256; ++k) orow[tid + 256 * k] = s_tags[tid + 256 * k];
}

extern "C" void kernel_launch(void* const* d_in, const int* in_sizes, int n_in,
                              void* d_out, int out_size, void* d_ws, size_t ws_size,
                              hipStream_t stream) {
    const float* feats = (const float*)d_in[0];
    const int*   mask  = (const int*)d_in[1];
    const float* trans = (const float*)d_in[2];
    int* out = (int*)d_out;
    viterbi_kernel<<<dim3(BB), dim3(256), 0, stream>>>(feats, mask, trans, out);
}

// Round 4
// 300.617 us; speedup vs baseline: 1.2467x; 1.2467x over previous
//
#include <hip/hip_runtime.h>

#define BB 64
#define LL 512
#define TT 52
#define START_TAG 50
#define END_TAG 51
#define CH 32               // steps per chunk
#define CF (CH * TT)        // floats per f-chunk = 1664

// R13: producer/consumer split (R12) with the f-buffer race fixed.
// R12 bug: feats triple-buffered, but iteration h has FOUR concurrent chunk
// users: wave0 reads chunk h, boundary-prefetches chunk h+1, stagers write
// chunk h+2, bp-recompute reads chunk h-1. (h+2)%3 == (h-1)%3 => stagers
// clobbered the chunk being recomputed (no intra-group barrier between the
// two phases). Fix: MOD-4 f window -> h, h+1, h+2, h+3(=h-1) pairwise
// distinct. P-window stays mod-3 (users h, h+1, h-1: distinct mod 3).
//
// Wave 0 runs the serial Viterbi recurrence ALONE, entirely in registers:
// 52 readlane + 104 add + max tree per step; no barrier, no LDS round-trip,
// no argmax, no global memory in the loop. Waves 1-7 trail one chunk behind:
// they recompute backpointers for chunk h-1 from the P-history window
// (bit-identical arithmetic => first value-match == jnp.argmax
// first-max-wins) and stage f chunk h+2. Their ~2-5 kcy/chunk hides under
// wave 0's ~13 kcy/chunk. One barrier per 32 steps.
// Exactness: recurrence order (f + c[i]) + P[i] identical to reference; max
// tree exact in any order; recompute uses the same staged bits (LDS copies)
// so bv is bit-identical; descending value-equality scan (last-write-wins)
// picks the smallest matching i == jnp.argmax (+-0 compares equal; fine).
__launch_bounds__(512, 2)
__global__ void viterbi_kernel(const float* __restrict__ feats,
                               const int* __restrict__ mask,
                               const float* __restrict__ trans,
                               int* __restrict__ out) {
    const int b    = blockIdx.x;
    const int tid  = threadIdx.x;
    const int lane = tid & 63;
    const int w    = tid >> 6;

    __shared__ float s_feat[4][CF];                // f chunks, QUAD-buffered (26624 B)
    __shared__ float s_pwin[3][CH + 1][TT];        // P history window (20592 B)
    __shared__ unsigned char s_bp[LL * TT];        // backpointers (26624 B)
    __shared__ float s_tr[TT * TT];                // transitions copy (10816 B)
    __shared__ int s_tags[LL];                     // decode (2048 B)
    __shared__ unsigned char s_map[8 * 52];
    __shared__ int s_ent[9];

    // ---- length n = sum(mask[b,:]) (every wave computes the same value) ----
    int partial = 0;
    const int* mrow = mask + b * LL;
    #pragma unroll
    for (int k = 0; k < LL / 64; ++k) partial += mrow[lane + 64 * k];
    #pragma unroll
    for (int off = 32; off >= 1; off >>= 1) partial += __shfl_xor(partial, off, 64);
    const int n = partial;            // uniform, in [256, 512]
    const int H = (n + CH - 1) / CH;  // chunks

    const int flane = (lane < TT) ? lane : (TT - 1);
    const float* frow = feats + (size_t)b * LL * TT;

    s_tags[tid] = 0;

    // ---- stage trans + f chunks 0,1 ----
    for (int e = tid; e < TT * TT; e += 512) s_tr[e] = trans[e];
    for (int e = tid; e < CF; e += 512) {
        s_feat[0][e] = frow[e];
        s_feat[1][e] = frow[CF + e];
    }

    // ---- P0 in-register (wave 0) + seed the P-window ----
    float bestP = -3.0e38f;
    if (w == 0) {
        bestP = (lane < TT) ? (frow[lane] + trans[START_TAG * TT + lane]) : -3.0e38f;
        if (lane < TT) s_pwin[0][1][lane] = bestP;   // P_0 at chunk-0 slot 1
    }
    __syncthreads();   // staging + P0 visible

    // ---- wave-0 registers ----
    float creg[TT];
    float tE = 0.0f, fcur = 0.0f;
    if (w == 0) {
        #pragma unroll
        for (int i = 0; i < TT; ++i) creg[i] = s_tr[i * TT + flane];
        tE   = s_tr[flane * TT + END_TAG];
        fcur = s_feat[0][1 * TT + flane];            // f for t=1
    }

    // ---- main loop: chunks of 32 steps, one barrier per chunk ----
    for (int h = 0; h < H; ++h) {
        if (w == 0) {
            // ======== forward chunk h (serial recurrence, register-only) ====
            const int tsta = (h == 0) ? 1 : CH * h;
            const int tend = (CH * (h + 1) < n) ? CH * (h + 1) : n;
            for (int t = tsta; t < tend; ++t) {
                // next-step f prefetch (LDS, ~entire body of cover)
                int tn = t + 1; if (tn > n - 1) tn = n - 1;
                float fnx = s_feat[(tn >> 5) & 3][(tn & (CH - 1)) * TT + flane];

                // bv[i] = (f + c[i]) + P[i]  -- exact reference order
                float bv[TT];
                #pragma unroll
                for (int i = 0; i < TT; ++i) {
                    float Pi = __int_as_float(
                        __builtin_amdgcn_readlane(__float_as_int(bestP), i));
                    bv[i] = (fcur + creg[i]) + Pi;
                }

                // 52-value max tree (max3-shaped; exact in any order)
                float l1[18];
                #pragma unroll
                for (int g = 0; g < 17; ++g)
                    l1[g] = fmaxf(fmaxf(bv[3 * g], bv[3 * g + 1]), bv[3 * g + 2]);
                l1[17] = bv[51];
                float l2[6];
                #pragma unroll
                for (int g = 0; g < 6; ++g)
                    l2[g] = fmaxf(fmaxf(l1[3 * g], l1[3 * g + 1]), l1[3 * g + 2]);
                float M = fmaxf(fmaxf(fmaxf(l2[0], l2[1]), fmaxf(l2[2], l2[3])),
                                fmaxf(l2[4], l2[5]));

                bestP = M;

                // publish P_t into the window (slot t-CH*h+1 of buffer h%3)
                if (lane < TT) {
                    s_pwin[h % 3][t - CH * h + 1][lane] = M;
                    // chunk-boundary: P_{CH(h+1)-1} is slot 0 of buffer (h+1)%3
                    if (t + 1 < n && t == CH * (h + 1) - 1)
                        s_pwin[(h + 1) % 3][0][lane] = M;
                }
                fcur = fnx;
            }
        } else {
            const int tid2 = tid - 64;   // 0..447
            // ======== stage f chunk h+2 into buffer (h+2)%4 ================
            if (CH * (h + 2) < n) {
                const float* sp = frow + (size_t)CH * (h + 2) * TT;
                float* dp = s_feat[(h + 2) & 3];
                for (int e = tid2; e < CF; e += 448) dp[e] = sp[e];
            }
            // ======== recompute backpointers for chunk h-1 (buffer (h-1)%4) =
            if (h >= 1) {
                const int hh   = h - 1;
                const int tsta = (hh == 0) ? 1 : CH * hh;
                const int tend = (CH * (hh + 1) < n) ? CH * (hh + 1) : n;
                const int cnt  = (tend - tsta) * TT;
                const float* fbuf = s_feat[hh & 3];
                const float* pbuf = &s_pwin[hh % 3][0][0];
                for (int e = tid2; e < cnt; e += 448) {
                    int trow = e / TT;
                    int j    = e - trow * TT;
                    int t    = tsta + trow;
                    int slotPrev = t - CH * hh;          // P_{t-1} slot
                    float Mv = pbuf[(slotPrev + 1) * TT + j];   // P_t[j]
                    float fv = fbuf[(t & (CH - 1)) * TT + j];
                    int idx = 0;
                    #pragma unroll 4
                    for (int i = TT - 1; i >= 0; --i) {
                        float bvv = (fv + s_tr[i * TT + j]) + pbuf[slotPrev * TT + i];
                        idx = (bvv == Mv) ? i : idx;     // smallest matching i wins
                    }
                    s_bp[t * TT + j] = (unsigned char)idx;
                }
            }
        }
        __syncthreads();
    }

    // ---- tail: ptr0 (wave 0) and the last chunk's backpointers (others) ----
    if (w == 0) {
        float lv = (lane < TT) ? (bestP + tE) : -3.0e38f;
        int li = lane;
        #pragma unroll
        for (int off = 32; off >= 1; off >>= 1) {
            float ov = __shfl_xor(lv, off, 64);
            int   oi = __shfl_xor(li, off, 64);
            if (ov > lv || (ov == lv && oi < li)) { lv = ov; li = oi; }
        }
        if (tid == 0) s_ent[8] = li;
    } else {
        const int tid2 = tid - 64;
        const int hh   = H - 1;
        const int tsta = (hh == 0) ? 1 : CH * hh;
        const int tend = n;
        const int cnt  = (tend - tsta) * TT;
        const float* fbuf = s_feat[hh & 3];
        const float* pbuf = &s_pwin[hh % 3][0][0];
        for (int e = tid2; e < cnt; e += 448) {
            int trow = e / TT;
            int j    = e - trow * TT;
            int t    = tsta + trow;
            int slotPrev = t - CH * hh;
            float Mv = pbuf[(slotPrev + 1) * TT + j];
            float fv = fbuf[(t & (CH - 1)) * TT + j];
            int idx = 0;
            #pragma unroll 4
            for (int i = TT - 1; i >= 0; --i) {
                float bvv = (fv + s_tr[i * TT + j]) + pbuf[slotPrev * TT + i];
                idx = (bvv == Mv) ? i : idx;
            }
            s_bp[t * TT + j] = (unsigned char)idx;
        }
    }
    __syncthreads();

    const int ptr0 = s_ent[8];

    // ---- backtrace: 8-chunk two-phase parallel pointer chase (512 thr) ----
    const int W  = n - 1;
    const int Sc = (W + 7) >> 3;
    if (tid < 416) {
        int k = tid / 52, y = tid - k * 52;
        int s0 = k * Sc, s1 = min(s0 + Sc, W);
        int x = y;
        for (int s = s0; s < s1; ++s) x = s_bp[(n - 1 - s) * TT + x];
        s_map[k * 52 + y] = (unsigned char)x;
    }
    __syncthreads();
    if (tid == 0) {
        int e = ptr0; s_ent[0] = e;
        #pragma unroll
        for (int k = 1; k < 8; ++k) { e = s_map[(k - 1) * 52 + e]; s_ent[k] = e; }
        s_tags[n - 1] = ptr0;
        s_tags[LL - 1] = ptr0;   // reference quirk: decode[L-1] = pointer0 always
    }
    __syncthreads();
    if (tid < 8) {
        int k = tid;
        int x = s_ent[k];
        int ss0 = k * Sc, ss1 = min(ss0 + Sc, W);
        for (int s = ss0; s < ss1; ++s) {
            x = s_bp[(n - 1 - s) * TT + x];
            s_tags[n - 2 - s] = x;
        }
    }
    __syncthreads();

    // ---- coalesced output write ----
    out[b * LL + tid] = s_tags[tid];
}

extern "C" void kernel_launch(void* const* d_in, const int* in_sizes, int n_in,
                              void* d_out, int out_size, void* d_ws, size_t ws_size,
                              hipStream_t stream) {
    const float* feats = (const float*)d_in[0];
    const int*   mask  = (const int*)d_in[1];
    const float* trans = (const float*)d_in[2];
    int* out = (int*)d_out;
    viterbi_kernel<<<dim3(BB), dim3(512), 0, stream>>>(feats, mask, trans, out);
}